// Round 2
// baseline (415.888 us; speedup 1.0000x reference)
//
#include <hip/hip_runtime.h>

// LayerGCN: out = relu(bn2(relu(bn1( (D^-.5 (A>=.1) D^-.5) V @ W1 )) @ W2))
// B=4096, N=128, C_IN=64, C_HID=256, C_OUT=128.
// R2: 512 blocks x 8 batches, register prefetch of next A/V (latency hiding),
// swapped-operand GEMM2 + k-permuted W2 so x1 never touches LDS.

#define THRESH 0.1f
#define BN_EPS 1e-5f
#define IT 8
#define GRID 512

typedef __attribute__((ext_vector_type(8))) short bf16x8;
typedef __attribute__((ext_vector_type(4))) float f32x4;
typedef __attribute__((ext_vector_type(4))) unsigned short u16x4;

__device__ __forceinline__ unsigned short f2bf(float f) {
    union { float f; unsigned u; } x; x.f = f;
    unsigned r = x.u + 0x7FFFu + ((x.u >> 16) & 1u);   // RNE
    return (unsigned short)(r >> 16);
}

__device__ __forceinline__ unsigned cvt_pk(float lo, float hi) {
    unsigned r;
    asm("v_cvt_pk_bf16_f32 %0, %1, %2" : "=v"(r) : "v"(lo), "v"(hi));
    return r;
}

// ---------------- prep: transpose+cast weights, fold BN ----------------
// W1t[n][k] = bf16(W1[k][n])  (256x64)
// W2p[n][k'] = bf16(W2[k][n]) (128x256) with k-permutation inside each 32-block:
//   k' fields {T=k'>>5, g=(k'>>3)&3, a=(k'>>2)&1, r=k'&3} <- k = 32T+16a+4g+r
// so GEMM3's A-side register layout (x1 cols 32T+16a+4g+r at slot j=(a<<2)|r of
// lane-group g) matches a plain contiguous-8 B-side load. k is summed -> legal.
__global__ void gcn_prep(const float* __restrict__ W1, const float* __restrict__ b1,
                         const float* __restrict__ g1, const float* __restrict__ be1,
                         const float* __restrict__ rm1, const float* __restrict__ rv1,
                         const float* __restrict__ W2, const float* __restrict__ b2,
                         const float* __restrict__ g2, const float* __restrict__ be2,
                         const float* __restrict__ rm2, const float* __restrict__ rv2,
                         unsigned short* __restrict__ W1t, unsigned short* __restrict__ W2p,
                         float* __restrict__ sc1, float* __restrict__ sh1,
                         float* __restrict__ sc2, float* __restrict__ sh2) {
    int t = blockIdx.x * blockDim.x + threadIdx.x;       // 0..32767
    if (t < 256 * 64) {                                  // W1t: n = t/64, k = t%64
        int n = t >> 6, k = t & 63;
        W1t[t] = f2bf(W1[k * 256 + n]);
    }
    {                                                    // W2p: n = t/256, k' = t%256
        int n = t >> 8, kp = t & 255;
        int r = kp & 3, aa = (kp >> 2) & 1, gg = (kp >> 3) & 3, T = kp >> 5;
        int k = T * 32 + aa * 16 + gg * 4 + r;
        W2p[t] = f2bf(W2[k * 128 + n]);
    }
    if (t < 256) {
        float s = g1[t] * rsqrtf(rv1[t] + BN_EPS);
        sc1[t] = s;
        sh1[t] = (b1[t] - rm1[t]) * s + be1[t];
    }
    if (t < 128) {
        float s = g2[t] * rsqrtf(rv2[t] + BN_EPS);
        sc2[t] = s;
        sh2[t] = (b2[t] - rm2[t]) * s + be2[t];
    }
}

// ---------------- main fused kernel ----------------
// LDS (55808 B): a_th [128][136]u16 @0 (34816, h overlays cols 0..63 per-wave rows)
//                vtt  [64][136] u16 @34816 (17408)
//                dinv f32[128] @52224 | sc1 @52736 | sh1 @53760 | sc2 @54784 | sh2 @55296
__global__ void __launch_bounds__(256, 2)
gcn_main(const float* __restrict__ A, const float* __restrict__ V,
         const unsigned short* __restrict__ W1t, const unsigned short* __restrict__ W2p,
         const float* __restrict__ sc1g, const float* __restrict__ sh1g,
         const float* __restrict__ sc2g, const float* __restrict__ sh2g,
         float* __restrict__ out) {
    __shared__ char smem[55808];
    unsigned short* s_ath = (unsigned short*)smem;            // stride 136
    unsigned short* s_vtt = (unsigned short*)(smem + 34816);  // stride 136
    float* s_dinv = (float*)(smem + 52224);
    float* s_sc1  = (float*)(smem + 52736);
    float* s_sh1  = (float*)(smem + 53760);
    float* s_sc2  = (float*)(smem + 54784);
    float* s_sh2  = (float*)(smem + 55296);

    const int t    = threadIdx.x;
    const int lane = t & 63;
    const int w    = t >> 6;       // wave 0..3 owns output rows 32w..32w+31
    const int r16  = lane & 15;
    const int g    = lane >> 4;

    s_sc1[t] = sc1g[t];
    s_sh1[t] = sh1g[t];
    if (t < 128) { s_sc2[t] = sc2g[t]; s_sh2[t] = sh2g[t]; }

    const int b0 = blockIdx.x * IT;

    // initial prefetch of batch b0
    f32x4 pa[16], pv[8];
    {
        const float* ab = A + (size_t)b0 * 16384;
        const float* vb = V + (size_t)b0 * 8192;
#pragma unroll
        for (int i = 0; i < 16; ++i) pa[i] = *(const f32x4*)(ab + 4 * t + 1024 * i);
#pragma unroll
        for (int i = 0; i < 8; ++i)  pv[i] = *(const f32x4*)(vb + 4 * t + 1024 * i);
    }

#pragma unroll 1
    for (int it = 0; it < IT; ++it) {
        // ---- threshold + degree (consumes pa) ----
#pragma unroll
        for (int i = 0; i < 16; ++i) {
            f32x4 x = pa[i];
            int row = (t >> 5) + 8 * i;
            int col = (4 * t) & 127;
            u16x4 th;
            th.x = (x.x >= THRESH) ? (unsigned short)0x3F80u : (unsigned short)0u;
            th.y = (x.y >= THRESH) ? (unsigned short)0x3F80u : (unsigned short)0u;
            th.z = (x.z >= THRESH) ? (unsigned short)0x3F80u : (unsigned short)0u;
            th.w = (x.w >= THRESH) ? (unsigned short)0x3F80u : (unsigned short)0u;
            *(u16x4*)(s_ath + row * 136 + col) = th;
            int cnt = (x.x >= THRESH) + (x.y >= THRESH) + (x.z >= THRESH) + (x.w >= THRESH);
#pragma unroll
            for (int s = 1; s < 32; s <<= 1) cnt += __shfl_xor(cnt, s);
            if ((lane & 31) == 0) s_dinv[row] = rsqrtf((float)cnt);
        }
        __syncthreads();   // (1) a_th + dinv visible

        // ---- vtt[c][m] = bf16(v[m][c] * dinv[m])  (consumes pv) ----
        {
            int m0 = t >> 4;
            int c0 = (4 * t) & 63;
#pragma unroll
            for (int i = 0; i < 8; ++i) {
                int m = m0 + 16 * i;
                float d = s_dinv[m];
                s_vtt[(c0 + 0) * 136 + m] = f2bf(pv[i].x * d);
                s_vtt[(c0 + 1) * 136 + m] = f2bf(pv[i].y * d);
                s_vtt[(c0 + 2) * 136 + m] = f2bf(pv[i].z * d);
                s_vtt[(c0 + 3) * 136 + m] = f2bf(pv[i].w * d);
            }
        }

        // ---- prefetch next batch's A/V (latency hides under GEMM phase) ----
        if (it + 1 < IT) {
            const float* abn = A + (size_t)(b0 + it + 1) * 16384;
            const float* vbn = V + (size_t)(b0 + it + 1) * 8192;
#pragma unroll
            for (int i = 0; i < 16; ++i) pa[i] = *(const f32x4*)(abn + 4 * t + 1024 * i);
#pragma unroll
            for (int i = 0; i < 8; ++i)  pv[i] = *(const f32x4*)(vbn + 4 * t + 1024 * i);
        }
        __syncthreads();   // (2) vtt ready

        // ---- GEMM1: h(32 rows/wave) = a_th @ vt, N=64, K=128 ----
        f32x4 acc1[2][4];
#pragma unroll
        for (int rt = 0; rt < 2; ++rt)
#pragma unroll
            for (int ct = 0; ct < 4; ++ct) acc1[rt][ct] = f32x4{0.f, 0.f, 0.f, 0.f};
#pragma unroll
        for (int ks = 0; ks < 4; ++ks) {
            bf16x8 af0 = *(const bf16x8*)(s_ath + (32 * w + r16) * 136 + ks * 32 + 8 * g);
            bf16x8 af1 = *(const bf16x8*)(s_ath + (32 * w + 16 + r16) * 136 + ks * 32 + 8 * g);
#pragma unroll
            for (int ct = 0; ct < 4; ++ct) {
                bf16x8 bf = *(const bf16x8*)(s_vtt + (ct * 16 + r16) * 136 + ks * 32 + 8 * g);
                acc1[0][ct] = __builtin_amdgcn_mfma_f32_16x16x32_bf16(af0, bf, acc1[0][ct], 0, 0, 0);
                acc1[1][ct] = __builtin_amdgcn_mfma_f32_16x16x32_bf16(af1, bf, acc1[1][ct], 0, 0, 0);
            }
        }
        // h = dinv[row]*acc -> bf16 into own-wave a_th rows, cols 0..63
        float dr[2][4];
#pragma unroll
        for (int rt = 0; rt < 2; ++rt)
#pragma unroll
            for (int r = 0; r < 4; ++r) dr[rt][r] = s_dinv[32 * w + rt * 16 + 4 * g + r];
#pragma unroll
        for (int rt = 0; rt < 2; ++rt)
#pragma unroll
            for (int ct = 0; ct < 4; ++ct)
#pragma unroll
                for (int r = 0; r < 4; ++r) {
                    int row = 32 * w + rt * 16 + 4 * g + r;
                    s_ath[row * 136 + ct * 16 + r16] = f2bf(acc1[rt][ct][r] * dr[rt][r]);
                }

        // ---- fused GEMM2 (swapped) + BN1/ReLU + GEMM3 ----
        // bh[mt][ks2]: h rows (B-operand, [m][k] layout), own-wave RAW via lgkmcnt
        bf16x8 bh[2][2];
#pragma unroll
        for (int mt = 0; mt < 2; ++mt)
#pragma unroll
            for (int ks2 = 0; ks2 < 2; ++ks2)
                bh[mt][ks2] = *(const bf16x8*)(s_ath + (32 * w + mt * 16 + r16) * 136 + ks2 * 32 + 8 * g);

        f32x4 acc3[2][8];
#pragma unroll
        for (int mt = 0; mt < 2; ++mt)
#pragma unroll
            for (int ct = 0; ct < 8; ++ct) acc3[mt][ct] = f32x4{0.f, 0.f, 0.f, 0.f};

#pragma unroll
        for (int T = 0; T < 8; ++T) {
            // GEMM2 for x1 col-tiles ct0=2T, ct1=2T+1 (D transposed: row=c, col=m)
            f32x4 a2[2][2];   // [mt][ctp]
#pragma unroll
            for (int mt = 0; mt < 2; ++mt)
#pragma unroll
                for (int ctp = 0; ctp < 2; ++ctp) a2[mt][ctp] = f32x4{0.f, 0.f, 0.f, 0.f};
#pragma unroll
            for (int ctp = 0; ctp < 2; ++ctp) {
                int ct = 2 * T + ctp;
#pragma unroll
                for (int ks2 = 0; ks2 < 2; ++ks2) {
                    bf16x8 aw = *(const bf16x8*)(W1t + (ct * 16 + r16) * 64 + ks2 * 32 + 8 * g);
                    a2[0][ctp] = __builtin_amdgcn_mfma_f32_16x16x32_bf16(aw, bh[0][ks2], a2[0][ctp], 0, 0, 0);
                    a2[1][ctp] = __builtin_amdgcn_mfma_f32_16x16x32_bf16(aw, bh[1][ks2], a2[1][ctp], 0, 0, 0);
                }
            }
            // BN1 + ReLU + pack. a2[mt][ctp][r] = x1_pre[m=mt*16+r16][c=(2T+ctp)*16+4g+r]
            unsigned wds[2][4];
#pragma unroll
            for (int ctp = 0; ctp < 2; ++ctp) {
                int c0 = (2 * T + ctp) * 16 + 4 * g;
                f32x4 sc = *(const f32x4*)(s_sc1 + c0);
                f32x4 sh = *(const f32x4*)(s_sh1 + c0);
#pragma unroll
                for (int mt = 0; mt < 2; ++mt) {
                    float y0 = fmaxf(fmaf(a2[mt][ctp][0], sc.x, sh.x), 0.f);
                    float y1 = fmaxf(fmaf(a2[mt][ctp][1], sc.y, sh.y), 0.f);
                    float y2 = fmaxf(fmaf(a2[mt][ctp][2], sc.z, sh.z), 0.f);
                    float y3 = fmaxf(fmaf(a2[mt][ctp][3], sc.w, sh.w), 0.f);
                    wds[mt][2 * ctp + 0] = cvt_pk(y0, y1);
                    wds[mt][2 * ctp + 1] = cvt_pk(y2, y3);
                }
            }
            // GEMM3 partial: A-slot j of lane-group g holds x1 col 32T+16(j>>2)+4g+(j&3);
            // W2p is pre-permuted to match -> plain contiguous B-load.
#pragma unroll
            for (int mt = 0; mt < 2; ++mt) {
                union { unsigned u[4]; bf16x8 v; } af;
                af.u[0] = wds[mt][0]; af.u[1] = wds[mt][1];
                af.u[2] = wds[mt][2]; af.u[3] = wds[mt][3];
#pragma unroll
                for (int ct3 = 0; ct3 < 8; ++ct3) {
                    bf16x8 bw = *(const bf16x8*)(W2p + (ct3 * 16 + r16) * 256 + T * 32 + 8 * g);
                    acc3[mt][ct3] = __builtin_amdgcn_mfma_f32_16x16x32_bf16(af.v, bw, acc3[mt][ct3], 0, 0, 0);
                }
            }
        }

        // ---- BN2 + ReLU -> global ----
        float* ob = out + (size_t)(b0 + it) * 16384;
#pragma unroll
        for (int ct3 = 0; ct3 < 8; ++ct3) {
            int c = ct3 * 16 + r16;
            float sc = s_sc2[c], sh = s_sh2[c];
#pragma unroll
            for (int mt = 0; mt < 2; ++mt)
#pragma unroll
                for (int r = 0; r < 4; ++r) {
                    int row = 32 * w + mt * 16 + 4 * g + r;
                    ob[row * 128 + c] = fmaxf(fmaf(acc3[mt][ct3][r], sc, sh), 0.f);
                }
        }
        __syncthreads();   // (3) all waves done with a_th/vtt/dinv before next iter
    }
}

extern "C" void kernel_launch(void* const* d_in, const int* in_sizes, int n_in,
                              void* d_out, int out_size, void* d_ws, size_t ws_size,
                              hipStream_t stream) {
    (void)in_sizes; (void)n_in; (void)out_size; (void)ws_size;
    const float* a   = (const float*)d_in[0];
    const float* v   = (const float*)d_in[1];
    const float* W1  = (const float*)d_in[2];
    const float* b1  = (const float*)d_in[3];
    const float* g1  = (const float*)d_in[4];
    const float* be1 = (const float*)d_in[5];
    const float* rm1 = (const float*)d_in[6];
    const float* rv1 = (const float*)d_in[7];
    const float* W2  = (const float*)d_in[8];
    const float* b2  = (const float*)d_in[9];
    const float* g2  = (const float*)d_in[10];
    const float* be2 = (const float*)d_in[11];
    const float* rm2 = (const float*)d_in[12];
    const float* rv2 = (const float*)d_in[13];

    char* ws = (char*)d_ws;
    unsigned short* W1t = (unsigned short*)ws;             // 32768 B
    unsigned short* W2p = (unsigned short*)(ws + 32768);   // 65536 B
    float* sc1 = (float*)(ws + 98304);
    float* sh1 = (float*)(ws + 99328);
    float* sc2 = (float*)(ws + 100352);
    float* sh2 = (float*)(ws + 100864);

    gcn_prep<<<128, 256, 0, stream>>>(W1, b1, g1, be1, rm1, rv1,
                                      W2, b2, g2, be2, rm2, rv2,
                                      W1t, W2p, sc1, sh1, sc2, sh2);
    gcn_main<<<GRID, 256, 0, stream>>>(a, v, W1t, W2p, sc1, sh1, sc2, sh2, (float*)d_out);
}

// Round 3
// 294.978 us; speedup vs baseline: 1.4099x; 1.4099x over previous
//
#include <hip/hip_runtime.h>

// LayerGCN: out = relu(bn2(relu(bn1( (D^-.5 (A>=.1) D^-.5) V @ W1 )) @ W2))
// B=4096, N=128, C_IN=64, C_HID=256, C_OUT=128.
// R3: a_th in register fragments (no LDS), wave-local dinv, ONE barrier/block,
// BN scales folded into bf16 weights, 3 blocks/CU.

#define THRESH 0.1f
#define BN_EPS 1e-5f

typedef __attribute__((ext_vector_type(8))) short bf16x8;
typedef __attribute__((ext_vector_type(4))) float f32x4;

__device__ __forceinline__ unsigned short f2bf(float f) {
    union { float f; unsigned u; } x; x.f = f;
    unsigned r = x.u + 0x7FFFu + ((x.u >> 16) & 1u);   // RNE
    return (unsigned short)(r >> 16);
}

__device__ __forceinline__ unsigned cvt_pk(float lo, float hi) {
    unsigned r;
    asm("v_cvt_pk_bf16_f32 %0, %1, %2" : "=v"(r) : "v"(lo), "v"(hi));
    return r;
}

// ---------------- prep: transpose+cast weights, fold BN scale into W ----------------
// W1t[n][k] = bf16(W1[k][n] * sc1[n])  (256x64)
// W2p[n][k'] = bf16(W2[k][n] * sc2[n]) (128x256), k' permuted so GEMM3's A-side
//   register layout (x1 col 32T+16(j>>2)+4g+(j&3) at slot j of lane-group g)
//   matches a contiguous-8 B-load: k = 32T+16a+4gg+r for k' fields
//   {T=k'>>5, gg=(k'>>3)&3, a=(k'>>2)&1, r=k'&3}. k is summed -> any shared bijection ok.
// sh1 = (b1-rm1)*sc1 + be1, sh2 = (b2-rm2)*sc2 + be2.
__global__ void gcn_prep(const float* __restrict__ W1, const float* __restrict__ b1,
                         const float* __restrict__ g1, const float* __restrict__ be1,
                         const float* __restrict__ rm1, const float* __restrict__ rv1,
                         const float* __restrict__ W2, const float* __restrict__ b2,
                         const float* __restrict__ g2, const float* __restrict__ be2,
                         const float* __restrict__ rm2, const float* __restrict__ rv2,
                         unsigned short* __restrict__ W1t, unsigned short* __restrict__ W2p,
                         float* __restrict__ sh1, float* __restrict__ sh2) {
    int t = blockIdx.x * blockDim.x + threadIdx.x;       // 0..32767
    if (t < 256 * 64) {                                  // W1t: n = t/64, k = t%64
        int n = t >> 6, k = t & 63;
        float sc = g1[n] * rsqrtf(rv1[n] + BN_EPS);
        W1t[t] = f2bf(W1[k * 256 + n] * sc);
    }
    {                                                    // W2p: n = t/256, k' = t%256
        int n = t >> 8, kp = t & 255;
        int r = kp & 3, aa = (kp >> 2) & 1, gg = (kp >> 3) & 3, T = kp >> 5;
        int k = T * 32 + aa * 16 + gg * 4 + r;
        float sc = g2[n] * rsqrtf(rv2[n] + BN_EPS);
        W2p[t] = f2bf(W2[k * 128 + n] * sc);
    }
    if (t < 256) {
        float s = g1[t] * rsqrtf(rv1[t] + BN_EPS);
        sh1[t] = (b1[t] - rm1[t]) * s + be1[t];
    }
    if (t < 128) {
        float s = g2[t] * rsqrtf(rv2[t] + BN_EPS);
        sh2[t] = (b2[t] - rm2[t]) * s + be2[t];
    }
}

// ---------------- main fused kernel ----------------
// LDS (37888 B): vtt [64][136]u16 @0 (17408) | h 4x[32][72]u16 @17408 (18432)
//                dinv f32[128] @35840 | sh1 f32[256] @36352 | sh2 f32[128] @37376
__global__ void __launch_bounds__(256, 3)
gcn_main(const float* __restrict__ A, const float* __restrict__ V,
         const unsigned short* __restrict__ W1t, const unsigned short* __restrict__ W2p,
         const float* __restrict__ sh1g, const float* __restrict__ sh2g,
         float* __restrict__ out) {
    __shared__ char smem[37888];
    unsigned short* s_vtt = (unsigned short*)smem;             // [64][136]
    unsigned short* s_h   = (unsigned short*)(smem + 17408);   // 4 x [32][72]
    float* s_dinv = (float*)(smem + 35840);
    float* s_sh1  = (float*)(smem + 36352);
    float* s_sh2  = (float*)(smem + 37376);

    const int t    = threadIdx.x;
    const int lane = t & 63;
    const int w    = t >> 6;       // wave owns rows 32w..32w+31 (A rows, V rows, out rows)
    const int r16  = lane & 15;
    const int g    = lane >> 4;
    const int b    = blockIdx.x;

    s_sh1[t] = sh1g[t];
    if (t < 128) s_sh2[t] = sh2g[t];

    // ---- V loads (own 32 rows), issued early; scaled after degrees known ----
    const int mloc  = lane & 31;
    const int chalf = (lane >> 5) * 32;
    const float* vb = V + (size_t)b * 8192 + (size_t)(32 * w + mloc) * 64 + chalf;
    f32x4 pv[8];
#pragma unroll
    for (int q = 0; q < 8; ++q) pv[q] = *(const f32x4*)(vb + 4 * q);

    // ---- A: own 32 rows -> threshold into register fragments + degree count ----
    const float* ab = A + (size_t)b * 16384 + (size_t)(32 * w + r16) * 128;
    bf16x8 afrag[2][4];
    int cnt0 = 0, cnt1 = 0;
#pragma unroll
    for (int rt = 0; rt < 2; ++rt)
#pragma unroll
        for (int ks = 0; ks < 4; ++ks) {
            const float* p = ab + rt * 2048 + ks * 32 + 8 * g;
            f32x4 x0 = *(const f32x4*)p;
            f32x4 x1 = *(const f32x4*)(p + 4);
            union { unsigned short s[8]; bf16x8 v; } u;
            u.s[0] = (x0.x >= THRESH) ? (unsigned short)0x3F80u : (unsigned short)0u;
            u.s[1] = (x0.y >= THRESH) ? (unsigned short)0x3F80u : (unsigned short)0u;
            u.s[2] = (x0.z >= THRESH) ? (unsigned short)0x3F80u : (unsigned short)0u;
            u.s[3] = (x0.w >= THRESH) ? (unsigned short)0x3F80u : (unsigned short)0u;
            u.s[4] = (x1.x >= THRESH) ? (unsigned short)0x3F80u : (unsigned short)0u;
            u.s[5] = (x1.y >= THRESH) ? (unsigned short)0x3F80u : (unsigned short)0u;
            u.s[6] = (x1.z >= THRESH) ? (unsigned short)0x3F80u : (unsigned short)0u;
            u.s[7] = (x1.w >= THRESH) ? (unsigned short)0x3F80u : (unsigned short)0u;
            afrag[rt][ks] = u.v;
            int c = (x0.x >= THRESH) + (x0.y >= THRESH) + (x0.z >= THRESH) + (x0.w >= THRESH)
                  + (x1.x >= THRESH) + (x1.y >= THRESH) + (x1.z >= THRESH) + (x1.w >= THRESH);
            if (rt == 0) cnt0 += c; else cnt1 += c;
        }
    // reduce across the 4 lanes sharing r16 (lanes r16, +16, +32, +48)
    cnt0 += __shfl_xor(cnt0, 16); cnt0 += __shfl_xor(cnt0, 32);
    cnt1 += __shfl_xor(cnt1, 16); cnt1 += __shfl_xor(cnt1, 32);
    float dinv0 = rsqrtf((float)cnt0);   // row 32w + r16
    float dinv1 = rsqrtf((float)cnt1);   // row 32w + 16 + r16
    if (g == 0) {
        s_dinv[32 * w + r16]      = dinv0;
        s_dinv[32 * w + 16 + r16] = dinv1;
    }

    // ---- vtt[c][m] = bf16(v[m][c] * dinv[m]) for own m; dinv is register-local ----
    {
        float dm = (lane & 16) ? dinv1 : dinv0;    // row mloc = 16*((lane>>4)&1) + r16
        int m = 32 * w + mloc;
#pragma unroll
        for (int q = 0; q < 8; ++q) {
            int c = chalf + 4 * q;
            s_vtt[(c + 0) * 136 + m] = f2bf(pv[q].x * dm);
            s_vtt[(c + 1) * 136 + m] = f2bf(pv[q].y * dm);
            s_vtt[(c + 2) * 136 + m] = f2bf(pv[q].z * dm);
            s_vtt[(c + 3) * 136 + m] = f2bf(pv[q].w * dm);
        }
    }
    __syncthreads();   // the ONLY block barrier: vtt (+dinv) published

    // ---- GEMM1: h[32 rows] = a_th @ vt, N=64, K=128 (A from regs, B from LDS) ----
    f32x4 acc1[2][4];
#pragma unroll
    for (int rt = 0; rt < 2; ++rt)
#pragma unroll
        for (int ct = 0; ct < 4; ++ct) acc1[rt][ct] = f32x4{0.f, 0.f, 0.f, 0.f};
#pragma unroll
    for (int ks = 0; ks < 4; ++ks)
#pragma unroll
        for (int ct = 0; ct < 4; ++ct) {
            bf16x8 bf = *(const bf16x8*)(s_vtt + (ct * 16 + r16) * 136 + ks * 32 + 8 * g);
            acc1[0][ct] = __builtin_amdgcn_mfma_f32_16x16x32_bf16(afrag[0][ks], bf, acc1[0][ct], 0, 0, 0);
            acc1[1][ct] = __builtin_amdgcn_mfma_f32_16x16x32_bf16(afrag[1][ks], bf, acc1[1][ct], 0, 0, 0);
        }
    // scale by dinv[row], write h to wave-private LDS (D rows 16rt+4g+r, col ct*16+r16)
    f32x4 dr0 = *(const f32x4*)(s_dinv + 32 * w + 4 * g);
    f32x4 dr1 = *(const f32x4*)(s_dinv + 32 * w + 16 + 4 * g);
    unsigned short* s_hw = s_h + w * (32 * 72);
#pragma unroll
    for (int ct = 0; ct < 4; ++ct)
#pragma unroll
        for (int r = 0; r < 4; ++r) {
            s_hw[(4 * g + r) * 72 + ct * 16 + r16]      = f2bf(acc1[0][ct][r] * dr0[r]);
            s_hw[(16 + 4 * g + r) * 72 + ct * 16 + r16] = f2bf(acc1[1][ct][r] * dr1[r]);
        }
    // read back h as B-fragments (own-wave RAW; compiler inserts lgkmcnt)
    bf16x8 bh[2][2];
#pragma unroll
    for (int mt = 0; mt < 2; ++mt)
#pragma unroll
        for (int ks2 = 0; ks2 < 2; ++ks2)
            bh[mt][ks2] = *(const bf16x8*)(s_hw + (16 * mt + r16) * 72 + ks2 * 32 + 8 * g);

    // ---- fused GEMM2 (swapped) + BN1-shift/ReLU + GEMM3 ----
    f32x4 acc3[2][8];
#pragma unroll
    for (int mt = 0; mt < 2; ++mt)
#pragma unroll
        for (int ct = 0; ct < 8; ++ct) acc3[mt][ct] = f32x4{0.f, 0.f, 0.f, 0.f};

#pragma unroll
    for (int T = 0; T < 8; ++T) {
        // GEMM2 for x1 col-tiles 2T, 2T+1: D[c][m] transposed
        f32x4 a2[2][2];
#pragma unroll
        for (int mt = 0; mt < 2; ++mt)
#pragma unroll
            for (int ctp = 0; ctp < 2; ++ctp) a2[mt][ctp] = f32x4{0.f, 0.f, 0.f, 0.f};
#pragma unroll
        for (int ctp = 0; ctp < 2; ++ctp) {
            int ct = 2 * T + ctp;
#pragma unroll
            for (int ks2 = 0; ks2 < 2; ++ks2) {
                bf16x8 aw = *(const bf16x8*)(W1t + (ct * 16 + r16) * 64 + ks2 * 32 + 8 * g);
                a2[0][ctp] = __builtin_amdgcn_mfma_f32_16x16x32_bf16(aw, bh[0][ks2], a2[0][ctp], 0, 0, 0);
                a2[1][ctp] = __builtin_amdgcn_mfma_f32_16x16x32_bf16(aw, bh[1][ks2], a2[1][ctp], 0, 0, 0);
            }
        }
        // BN1 shift + ReLU + pack: a2[mt][ctp][r] = x1_pre[m=16mt+r16][c=(2T+ctp)*16+4g+r]
        unsigned wds[2][4];
#pragma unroll
        for (int ctp = 0; ctp < 2; ++ctp) {
            f32x4 sh = *(const f32x4*)(s_sh1 + (2 * T + ctp) * 16 + 4 * g);
#pragma unroll
            for (int mt = 0; mt < 2; ++mt) {
                float y0 = fmaxf(a2[mt][ctp][0] + sh.x, 0.f);
                float y1 = fmaxf(a2[mt][ctp][1] + sh.y, 0.f);
                float y2 = fmaxf(a2[mt][ctp][2] + sh.z, 0.f);
                float y3 = fmaxf(a2[mt][ctp][3] + sh.w, 0.f);
                wds[mt][2 * ctp + 0] = cvt_pk(y0, y1);
                wds[mt][2 * ctp + 1] = cvt_pk(y2, y3);
            }
        }
        // GEMM3 partial over k' = 32T..32T+31 (W2p pre-permuted to match reg layout)
#pragma unroll
        for (int mt = 0; mt < 2; ++mt) {
            union { unsigned u[4]; bf16x8 v; } af;
            af.u[0] = wds[mt][0]; af.u[1] = wds[mt][1];
            af.u[2] = wds[mt][2]; af.u[3] = wds[mt][3];
#pragma unroll
            for (int ct3 = 0; ct3 < 8; ++ct3) {
                bf16x8 bw = *(const bf16x8*)(W2p + (ct3 * 16 + r16) * 256 + T * 32 + 8 * g);
                acc3[mt][ct3] = __builtin_amdgcn_mfma_f32_16x16x32_bf16(af.v, bw, acc3[mt][ct3], 0, 0, 0);
            }
        }
    }

    // ---- BN2 shift + ReLU -> global ----
    float* ob = out + (size_t)b * 16384;
#pragma unroll
    for (int ct3 = 0; ct3 < 8; ++ct3) {
        int c = ct3 * 16 + r16;
        float sh = s_sh2[c];
#pragma unroll
        for (int mt = 0; mt < 2; ++mt)
#pragma unroll
            for (int r = 0; r < 4; ++r) {
                int row = 32 * w + 16 * mt + 4 * g + r;
                ob[row * 128 + c] = fmaxf(acc3[mt][ct3][r] + sh, 0.f);
            }
    }
}

extern "C" void kernel_launch(void* const* d_in, const int* in_sizes, int n_in,
                              void* d_out, int out_size, void* d_ws, size_t ws_size,
                              hipStream_t stream) {
    (void)in_sizes; (void)n_in; (void)out_size; (void)ws_size;
    const float* a   = (const float*)d_in[0];
    const float* v   = (const float*)d_in[1];
    const float* W1  = (const float*)d_in[2];
    const float* b1  = (const float*)d_in[3];
    const float* g1  = (const float*)d_in[4];
    const float* be1 = (const float*)d_in[5];
    const float* rm1 = (const float*)d_in[6];
    const float* rv1 = (const float*)d_in[7];
    const float* W2  = (const float*)d_in[8];
    const float* b2  = (const float*)d_in[9];
    const float* g2  = (const float*)d_in[10];
    const float* be2 = (const float*)d_in[11];
    const float* rm2 = (const float*)d_in[12];
    const float* rv2 = (const float*)d_in[13];

    char* ws = (char*)d_ws;
    unsigned short* W1t = (unsigned short*)ws;             // 32768 B
    unsigned short* W2p = (unsigned short*)(ws + 32768);   // 65536 B
    float* sh1 = (float*)(ws + 98304);                     // 1024 B
    float* sh2 = (float*)(ws + 99328);                     // 512 B

    gcn_prep<<<128, 256, 0, stream>>>(W1, b1, g1, be1, rm1, rv1,
                                      W2, b2, g2, be2, rm2, rv2,
                                      W1t, W2p, sh1, sh2);
    gcn_main<<<4096, 256, 0, stream>>>(a, v, W1t, W2p, sh1, sh2, (float*)d_out);
}